// Round 12
// baseline (463.649 us; speedup 1.0000x reference)
//
#include <hip/hip_runtime.h>
#include <stdint.h>

typedef unsigned short u16;
typedef short bf16x8 __attribute__((ext_vector_type(8)));
typedef float f32x4 __attribute__((ext_vector_type(4)));
typedef unsigned long long ull;

#define NB 8
#define NROW 4096
#define ND 768
#define NKB 24          // 768 / 32
#define NRB 32          // 4096 / 128
#define KTILE 4096      // u16 elements per 128x32 tile (8192 bytes)
#define NTRI 528        // 32*33/2 upper-triangular tile pairs
#define TOPK 50

// ---- workspace layout (bytes); ~361 MB total (r3-r11 proved ws >= this) ----
#define CPART_OFF 0u            // 8*32*768*4 = 786432
#define CSUM_OFF  786432u
#define MEAN_OFF  811008u
#define RV_OFF    835584u
#define XW_OFF    966656u
#define T_OFF     1097728u
#define U_OFF     1228800u
#define SMALL_TOTAL 1359872u
#define HI_OFF    ((size_t)SMALL_TOTAL)                 // 8 * 6291456
#define LO_OFF    (HI_OFF + 50331648ull)
#define COV_OFF   (LO_OFF + 50331648ull)                // 8 * 34603008

static __device__ __forceinline__ u16 f2bf(float f) {
  uint32_t u = __float_as_uint(f);
  u += 0x7FFFu + ((u >> 16) & 1u);   // RNE
  return (u16)(u >> 16);
}
static __device__ __forceinline__ float bf2f(u16 h) {
  return __uint_as_float(((uint32_t)h) << 16);
}

// async global->LDS, 16B per lane (dest = wave-uniform base + lane*16)
static __device__ __forceinline__ void gload_lds16(const char* g, char* l) {
  __builtin_amdgcn_global_load_lds(
      (const __attribute__((address_space(1))) uint32_t*)(const void*)g,
      (__attribute__((address_space(3))) uint32_t*)(void*)l, 16, 0, 0);
}

// bijective XCD swizzle for 528 tiles (528 % 8 == 0, 66 per XCD chunk)
static __device__ __forceinline__ int tile_swz(int t) {
  return (t & 7) * 66 + (t >> 3);
}

// ---------------- column mean (two-stage, deterministic) ----------------
__global__ __launch_bounds__(256)
void colsum1_kernel(const float* __restrict__ X, float* __restrict__ part) {
  const int nc = blockIdx.x;            // 0..31
  const int d  = threadIdx.x + blockIdx.y * 256;
  const int b  = blockIdx.z;
  const float* p = X + ((size_t)b * NROW + (size_t)nc * 128) * ND + d;
  float s = 0.f;
  for (int i = 0; i < 128; ++i) s += p[(size_t)i * ND];
  part[((size_t)b * 32 + nc) * ND + d] = s;
}

__global__ __launch_bounds__(256)
void colsum2_kernel(const float* __restrict__ part, float* __restrict__ csum,
                    float* __restrict__ mean) {
  const int d = threadIdx.x + blockIdx.x * 256;
  const int b = blockIdx.y;
  float s = 0.f;
  for (int i = 0; i < 32; ++i) s += part[((size_t)b * 32 + i) * ND + d];
  csum[(size_t)b * ND + d] = s;
  mean[(size_t)b * ND + d] = s * (1.0f / 4096.0f);
}

// ---------------- per-row stats + hi/lo split into swizzled tiles ----------------
__global__ __launch_bounds__(128)
void rowstats_kernel(const float* __restrict__ X, const float* __restrict__ W,
                     const float* __restrict__ mean,
                     u16* __restrict__ hi, u16* __restrict__ lo,
                     float* __restrict__ rv, float* __restrict__ xw) {
  const int n  = blockIdx.x;
  const int gb = blockIdx.y;
  const int tid = threadIdx.x;
  const float* xr = X + ((size_t)gb * NROW + n) * ND;
  const float* mb = mean + (size_t)gb * ND;
  const int r = n & 127, rbk = n >> 7;
  float ssq = 0.f, sw = 0.f;
  if (tid < 96) {
    const int d0 = tid * 8;
    const float4 xa = *(const float4*)(xr + d0);
    const float4 xb = *(const float4*)(xr + d0 + 4);
    const float4 ma = *(const float4*)(mb + d0);
    const float4 mc = *(const float4*)(mb + d0 + 4);
    const float4 wa = *(const float4*)(W + d0);
    const float4 wb = *(const float4*)(W + d0 + 4);
    float x[8]  = {xa.x, xa.y, xa.z, xa.w, xb.x, xb.y, xb.z, xb.w};
    float mm[8] = {ma.x, ma.y, ma.z, ma.w, mc.x, mc.y, mc.z, mc.w};
    float ww[8] = {wa.x, wa.y, wa.z, wa.w, wb.x, wb.y, wb.z, wb.w};
    u16 hbits[8], lbits[8];
#pragma unroll
    for (int i = 0; i < 8; ++i) {
      float xc = x[i] - mm[i];
      ssq += xc * xc;
      sw  += x[i] * ww[i];
      u16 hb = f2bf(xc);
      float hf = bf2f(hb);
      u16 lb2 = f2bf(xc - hf);
      hbits[i] = hb; lbits[i] = lb2;
    }
    const int kb = d0 >> 5;
    const int kk = d0 & 31;
    const size_t tbyte = ((size_t)((gb * NRB + rbk) * NKB + kb)) * 8192
                       + (size_t)((r * 64 + kk * 2) ^ ((r & 7) << 4));
    uint4 hv, lv;
    hv.x = (uint32_t)hbits[0] | ((uint32_t)hbits[1] << 16);
    hv.y = (uint32_t)hbits[2] | ((uint32_t)hbits[3] << 16);
    hv.z = (uint32_t)hbits[4] | ((uint32_t)hbits[5] << 16);
    hv.w = (uint32_t)hbits[6] | ((uint32_t)hbits[7] << 16);
    lv.x = (uint32_t)lbits[0] | ((uint32_t)lbits[1] << 16);
    lv.y = (uint32_t)lbits[2] | ((uint32_t)lbits[3] << 16);
    lv.z = (uint32_t)lbits[4] | ((uint32_t)lbits[5] << 16);
    lv.w = (uint32_t)lbits[6] | ((uint32_t)lbits[7] << 16);
    *(uint4*)((char*)hi + tbyte) = hv;
    *(uint4*)((char*)lo + tbyte) = lv;
  }
#pragma unroll
  for (int m = 1; m < 64; m <<= 1) {
    ssq += __shfl_xor(ssq, m, 64);
    sw  += __shfl_xor(sw, m, 64);
  }
  __shared__ float sh[4];
  const int w = tid >> 6, lane = tid & 63;
  if (lane == 0) { sh[w * 2] = ssq; sh[w * 2 + 1] = sw; }
  __syncthreads();
  if (tid == 0) {
    float S = sh[0] + sh[2];
    float T = sh[1] + sh[3];
    const size_t i = (size_t)gb * NROW + n;
    rv[i] = 1.0f / (sqrtf(S) + 1e-6f);
    xw[i] = T;
  }
}

// ---------------- triangular cov GEMM: t-reduction + |cov| fp32 store ----------------
// r6/r8-proven structure: 16x16x32, single buffer, 2 __syncthreads, gload_lds16.
// cov stored with PLAIN stores (r11 showed NT stores cost gemm ~12 us via forced HBM writes).
static __device__ __forceinline__ bf16x8 read_frag(const u16* sm, int r, int kbyte) {
  const int byte = (r * 64 + kbyte) ^ ((r & 7) << 4);
  return *(const bf16x8*)((const char*)sm + byte);
}

__global__ __launch_bounds__(256, 2)
void gemm_acc_kernel(const u16* __restrict__ hi, const u16* __restrict__ lo,
                     const float* __restrict__ coef, float* __restrict__ outacc,
                     float* __restrict__ covout) {
  const int gb = blockIdx.y;
  const int tsw = tile_swz(blockIdx.x);
  int trem = tsw;
  int rb = 0;
  while (trem >= NRB - rb) { trem -= NRB - rb; ++rb; }
  const int cb = rb + trem;

  __shared__ u16 sm[4 * KTILE];     // 32 KiB: aHi | bHi | aLo | bLo
  u16* aHi = sm;
  u16* bHi = sm + KTILE;
  u16* aLo = sm + 2 * KTILE;
  u16* bLo = sm + 3 * KTILE;

  const int tid = threadIdx.x;
  const int lane = tid & 63;
  const int wid = tid >> 6;
  const int wrow = wid >> 1, wcol = wid & 1;
  const int l15 = lane & 15, lg = lane >> 4;

  const char* hA = (const char*)(hi + (size_t)((gb * NRB + rb) * NKB) * KTILE);
  const char* hB = (const char*)(hi + (size_t)((gb * NRB + cb) * NKB) * KTILE);
  const char* lA = (const char*)(lo + (size_t)((gb * NRB + rb) * NKB) * KTILE);
  const char* lB = (const char*)(lo + (size_t)((gb * NRB + cb) * NKB) * KTILE);

  f32x4 acc[4][4];
#pragma unroll
  for (int i = 0; i < 4; ++i)
#pragma unroll
    for (int j = 0; j < 4; ++j) acc[i][j] = f32x4{0.f, 0.f, 0.f, 0.f};

  for (int kb = 0; kb < NKB; ++kb) {
    __syncthreads();                       // all waves done reading previous tile
    const size_t kb8 = (size_t)kb * 8192;
#pragma unroll
    for (int it = 0; it < 2; ++it) {
      const int off = it * 4096 + tid * 16;
      gload_lds16(hA + kb8 + off, (char*)aHi + off);
      gload_lds16(hB + kb8 + off, (char*)bHi + off);
      gload_lds16(lA + kb8 + off, (char*)aLo + off);
      gload_lds16(lB + kb8 + off, (char*)bLo + off);
    }
    __syncthreads();                       // compiler drains vmcnt(0) -> LDS ready

    bf16x8 ah[4], bh[4], al[4], bl[4];
#pragma unroll
    for (int i = 0; i < 4; ++i) {
      ah[i] = read_frag(aHi, wrow * 64 + i * 16 + l15, lg * 16);
      bh[i] = read_frag(bHi, wcol * 64 + i * 16 + l15, lg * 16);
      al[i] = read_frag(aLo, wrow * 64 + i * 16 + l15, lg * 16);
      bl[i] = read_frag(bLo, wcol * 64 + i * 16 + l15, lg * 16);
    }
#pragma unroll
    for (int mi = 0; mi < 4; ++mi)
#pragma unroll
      for (int ni = 0; ni < 4; ++ni) {
        acc[mi][ni] = __builtin_amdgcn_mfma_f32_16x16x32_bf16(ah[mi], bh[ni], acc[mi][ni], 0, 0, 0);
        acc[mi][ni] = __builtin_amdgcn_mfma_f32_16x16x32_bf16(ah[mi], bl[ni], acc[mi][ni], 0, 0, 0);
        acc[mi][ni] = __builtin_amdgcn_mfma_f32_16x16x32_bf16(al[mi], bh[ni], acc[mi][ni], 0, 0, 0);
      }
  }

  const float* cf = coef + (size_t)gb * NROW;
  float* oa = outacc + (size_t)gb * NROW;
  const int rbase = rb * 128 + wrow * 64;
  const int cbase = cb * 128 + wcol * 64;

  // store |cov| tile (fp32, tile-linear 128x128) for the u-pass
  float* cv = covout + ((size_t)gb * NTRI + tsw) * 16384;
#pragma unroll
  for (int mi = 0; mi < 4; ++mi)
#pragma unroll
    for (int ni = 0; ni < 4; ++ni)
#pragma unroll
      for (int j = 0; j < 4; ++j)
        cv[(wrow * 64 + mi * 16 + lg * 4 + j) * 128 + wcol * 64 + ni * 16 + l15] =
            fabsf(acc[mi][ni][j]);

  // row-direction: t[row] += sum_cols |c| * coef[col]
  float ccol[4];
#pragma unroll
  for (int ni = 0; ni < 4; ++ni) ccol[ni] = cf[cbase + ni * 16 + l15];

  float rs[4][4];
#pragma unroll
  for (int mi = 0; mi < 4; ++mi)
#pragma unroll
    for (int j = 0; j < 4; ++j) {
      float s = 0.f;
#pragma unroll
      for (int ni = 0; ni < 4; ++ni) s += fabsf(acc[mi][ni][j]) * ccol[ni];
      rs[mi][j] = s;
    }
#pragma unroll
  for (int m = 1; m < 16; m <<= 1)
#pragma unroll
    for (int mi = 0; mi < 4; ++mi)
#pragma unroll
      for (int j = 0; j < 4; ++j) rs[mi][j] += __shfl_xor(rs[mi][j], m, 64);
  if (l15 == 0) {
#pragma unroll
    for (int mi = 0; mi < 4; ++mi)
#pragma unroll
      for (int j = 0; j < 4; ++j)
        atomicAdd(&oa[rbase + mi * 16 + lg * 4 + j], rs[mi][j]);
  }

  // col-direction (symmetry): off-diagonal tiles only
  if (rb != cb) {
    float crow[4][4];
#pragma unroll
    for (int mi = 0; mi < 4; ++mi)
#pragma unroll
      for (int j = 0; j < 4; ++j) crow[mi][j] = cf[rbase + mi * 16 + lg * 4 + j];
    float cs[4];
#pragma unroll
    for (int ni = 0; ni < 4; ++ni) {
      float s = 0.f;
#pragma unroll
      for (int mi = 0; mi < 4; ++mi)
#pragma unroll
        for (int j = 0; j < 4; ++j) s += fabsf(acc[mi][ni][j]) * crow[mi][j];
      cs[ni] = s;
    }
#pragma unroll
    for (int ni = 0; ni < 4; ++ni) {
      cs[ni] += __shfl_xor(cs[ni], 16, 64);
      cs[ni] += __shfl_xor(cs[ni], 32, 64);
    }
    if (lg == 0) {
#pragma unroll
      for (int ni = 0; ni < 4; ++ni)
        atomicAdd(&oa[cbase + ni * 16 + l15], cs[ni]);
    }
  }
}

// ---------------- u-pass: weighted row/col reduction of stored |cov| ----------------
// Row reduction via LDS transpose (no serial shfl chains); nontemporal cov loads.
__global__ __launch_bounds__(256, 2)
void upass_kernel(const float* __restrict__ cov, const float* __restrict__ tt,
                  const float* __restrict__ rv, const float* __restrict__ xw,
                  float* __restrict__ uacc) {
  const int gb = blockIdx.y;
  const int tsw = tile_swz(blockIdx.x);
  int trem = tsw;
  int rb = 0;
  while (trem >= NRB - rb) { trem -= NRB - rb; ++rb; }
  const int cb = rb + trem;

  const float* A = cov + ((size_t)gb * NTRI + tsw) * 16384;
  const size_t bo = (size_t)gb * NROW;

  __shared__ float wr[128];
  __shared__ float plds[128 * 33];       // [row][lane] partial row-dots, pad 33
  __shared__ float csum_p[8][128];

  const int t = threadIdx.x;
  const int g = t >> 5;          // 0..7
  const int l = t & 31;          // 0..31

  if (t < 128) {
    const int row = rb * 128 + t;
    wr[t] = (1.0f / sqrtf(rv[bo + row] * tt[bo + row])) * xw[bo + row] * rv[bo + row];
  }
  float4 wc4;
  {
    const int col = cb * 128 + l * 4;
    const float4 r4 = *(const float4*)(rv + bo + col);
    const float4 t4 = *(const float4*)(tt + bo + col);
    const float4 x4 = *(const float4*)(xw + bo + col);
    wc4.x = (1.0f / sqrtf(r4.x * t4.x)) * x4.x * r4.x;
    wc4.y = (1.0f / sqrtf(r4.y * t4.y)) * x4.y * r4.y;
    wc4.z = (1.0f / sqrtf(r4.z * t4.z)) * x4.z * r4.z;
    wc4.w = (1.0f / sqrtf(r4.w * t4.w)) * x4.w * r4.w;
  }
  __syncthreads();

  float sc0 = 0.f, sc1 = 0.f, sc2 = 0.f, sc3 = 0.f;
#pragma unroll
  for (int i = 0; i < 16; ++i) {
    const int r = g + i * 8;
    const f32x4 v = __builtin_nontemporal_load((const f32x4*)(A + r * 128 + l * 4));
    plds[r * 33 + l] = v[0] * wc4.x + v[1] * wc4.y + v[2] * wc4.z + v[3] * wc4.w;
    const float wrr = wr[r];
    sc0 += v[0] * wrr; sc1 += v[1] * wrr; sc2 += v[2] * wrr; sc3 += v[3] * wrr;
  }
  csum_p[g][l * 4 + 0] = sc0;
  csum_p[g][l * 4 + 1] = sc1;
  csum_p[g][l * 4 + 2] = sc2;
  csum_p[g][l * 4 + 3] = sc3;
  __syncthreads();

  float* ua = uacc + bo;
  if (t < 128) {
    float rsum = 0.f;
#pragma unroll
    for (int i = 0; i < 32; ++i) rsum += plds[t * 33 + i];
    atomicAdd(&ua[rb * 128 + t], rsum);
    if (rb != cb) {
      float s = 0.f;
#pragma unroll
      for (int gg = 0; gg < 8; ++gg) s += csum_p[gg][t];
      atomicAdd(&ua[cb * 128 + t], s);
    }
  }
}

// ---------------- top-k with fused S computation + gather + means ----------------
__global__ __launch_bounds__(1024)
void topk_kernel(const float* __restrict__ tt, const float* __restrict__ rv,
                 const float* __restrict__ u, const float* __restrict__ X,
                 const float* __restrict__ csum, float* __restrict__ S,
                 float* __restrict__ outFc, float* __restrict__ outC,
                 float* __restrict__ outNC) {
  const int b = blockIdx.x;
  __shared__ ull keys[NROW];
  __shared__ ull wred[16];
  __shared__ int selLds[TOPK];
  const int t = threadIdx.x;
  const int lane = t & 63, w = t >> 6;
  const size_t bo = (size_t)b * NROW;
#pragma unroll
  for (int j = 0; j < 4; ++j) {
    const int i = t + j * 1024;
    const float rvi = rv[bo + i];
    const float s = (1.0f / sqrtf(rvi * tt[bo + i])) * rvi * u[bo + i];
    S[bo + i] = s;
    uint32_t uu = __float_as_uint(s);
    uu = (uu & 0x80000000u) ? ~uu : (uu | 0x80000000u);
    keys[i] = ((ull)uu << 32) | (uint32_t)(4095 - i);
  }
  __syncthreads();
  for (int r = 0; r < TOPK; ++r) {
    ull m = keys[t];
    ull m2 = keys[t + 1024]; if (m2 > m) m = m2;
    m2 = keys[t + 2048]; if (m2 > m) m = m2;
    m2 = keys[t + 3072]; if (m2 > m) m = m2;
#pragma unroll
    for (int sh = 1; sh < 64; sh <<= 1) {
      ull o = __shfl_xor(m, sh, 64);
      if (o > m) m = o;
    }
    if (lane == 0) wred[w] = m;
    __syncthreads();
    if (w == 0) {
      ull mm = wred[lane & 15];
#pragma unroll
      for (int sh = 1; sh < 16; sh <<= 1) {
        ull o = __shfl_xor(mm, sh, 64);
        if (o > mm) mm = o;
      }
      if (lane == 0) {
        const int sel = 4095 - (int)(mm & 0xFFFFFFFFu);
        selLds[r] = sel;
        keys[sel] = 0ULL;
      }
    }
    __syncthreads();
  }

  // gather + means with threads 0..767 (selection indices in LDS)
  if (t < ND) {
    float s = 0.f;
    for (int r = 0; r < TOPK; ++r) {
      const int row = selLds[r];
      const float v = X[(bo + row) * ND + t];
      outFc[((size_t)b * TOPK + r) * ND + t] = v;
      s += v;
    }
    outC[(size_t)b * ND + t]  = s * (1.0f / 50.0f);
    outNC[(size_t)b * ND + t] = (csum[(size_t)b * ND + t] - s) * (1.0f / 4046.0f);
  }
}

// ---------------- launch ----------------
extern "C" void kernel_launch(void* const* d_in, const int* in_sizes, int n_in,
                              void* d_out, int out_size, void* d_ws, size_t ws_size,
                              hipStream_t stream) {
  const float* X = (const float*)d_in[0];
  const float* W = (const float*)d_in[1];
  float* out = (float*)d_out;
  char* ws = (char*)d_ws;

  float* cpart = (float*)(ws + CPART_OFF);
  float* csum  = (float*)(ws + CSUM_OFF);
  float* mean  = (float*)(ws + MEAN_OFF);
  float* rv    = (float*)(ws + RV_OFF);
  float* xw    = (float*)(ws + XW_OFF);
  float* tacc  = (float*)(ws + T_OFF);
  float* uacc  = (float*)(ws + U_OFF);
  u16* hi      = (u16*)(ws + HI_OFF);
  u16* lo      = (u16*)(ws + LO_OFF);
  float* cov   = (float*)(ws + COV_OFF);

  float* outS  = out;                       // 8*4096
  float* outFc = out + 32768;               // 8*50*768
  float* outMC = out + 339968;              // 8*768
  float* outMN = out + 346112;              // 8*768

  // zero the atomic accumulators (t and u are adjacent)
  hipMemsetAsync(ws + T_OFF, 0, 262144, stream);

  colsum1_kernel<<<dim3(32, 3, NB), 256, 0, stream>>>(X, cpart);
  colsum2_kernel<<<dim3(3, NB), 256, 0, stream>>>(cpart, csum, mean);
  rowstats_kernel<<<dim3(NROW, NB), 128, 0, stream>>>(X, W, mean, hi, lo, rv, xw);
  gemm_acc_kernel<<<dim3(NTRI, NB), 256, 0, stream>>>(hi, lo, rv, tacc, cov);
  upass_kernel<<<dim3(NTRI, NB), 256, 0, stream>>>(cov, tacc, rv, xw, uacc);
  topk_kernel<<<NB, 1024, 0, stream>>>(tacc, rv, uacc, X, csum, outS, outFc, outMC, outMN);
}

// Round 14
// 431.357 us; speedup vs baseline: 1.0749x; 1.0749x over previous
//
#include <hip/hip_runtime.h>
#include <stdint.h>

typedef unsigned short u16;
typedef short bf16x8 __attribute__((ext_vector_type(8)));
typedef float f32x4 __attribute__((ext_vector_type(4)));
typedef unsigned long long ull;

#define NB 8
#define NROW 4096
#define ND 768
#define NKB 24          // 768 / 32
#define NRB 32          // 4096 / 128
#define KTILE 4096      // u16 elements per 128x32 tile (8192 bytes)
#define NTRI 528        // 32*33/2 upper-triangular tile pairs
#define TOPK 50

// ---- workspace layout (bytes); ~361 MB total (r3-r12 proved ws >= this) ----
#define CPART_OFF 0u            // 8*32*768*4 = 786432
#define CSUM_OFF  786432u
#define MEAN_OFF  811008u
#define RV_OFF    835584u
#define XW_OFF    966656u
#define T_OFF     1097728u
#define U_OFF     1228800u
#define SMALL_TOTAL 1359872u
#define HI_OFF    ((size_t)SMALL_TOTAL)                 // 8 * 6291456
#define LO_OFF    (HI_OFF + 50331648ull)
#define COV_OFF   (LO_OFF + 50331648ull)                // 8 * 34603008

static __device__ __forceinline__ u16 f2bf(float f) {
  uint32_t u = __float_as_uint(f);
  u += 0x7FFFu + ((u >> 16) & 1u);   // RNE
  return (u16)(u >> 16);
}
static __device__ __forceinline__ float bf2f(u16 h) {
  return __uint_as_float(((uint32_t)h) << 16);
}

// async global->LDS, 16B per lane (dest = wave-uniform base + lane*16)
static __device__ __forceinline__ void gload_lds16(const char* g, char* l) {
  __builtin_amdgcn_global_load_lds(
      (const __attribute__((address_space(1))) uint32_t*)(const void*)g,
      (__attribute__((address_space(3))) uint32_t*)(void*)l, 16, 0, 0);
}

// bijective XCD swizzle for 528 tiles (528 % 8 == 0, 66 per XCD chunk)
static __device__ __forceinline__ int tile_swz(int t) {
  return (t & 7) * 66 + (t >> 3);
}

// ---------------- column mean (two-stage, deterministic) ----------------
__global__ __launch_bounds__(256)
void colsum1_kernel(const float* __restrict__ X, float* __restrict__ part) {
  const int nc = blockIdx.x;            // 0..31
  const int d  = threadIdx.x + blockIdx.y * 256;
  const int b  = blockIdx.z;
  const float* p = X + ((size_t)b * NROW + (size_t)nc * 128) * ND + d;
  float s = 0.f;
  for (int i = 0; i < 128; ++i) s += p[(size_t)i * ND];
  part[((size_t)b * 32 + nc) * ND + d] = s;
}

__global__ __launch_bounds__(256)
void colsum2_kernel(const float* __restrict__ part, float* __restrict__ csum,
                    float* __restrict__ mean) {
  const int d = threadIdx.x + blockIdx.x * 256;
  const int b = blockIdx.y;
  float s = 0.f;
  for (int i = 0; i < 32; ++i) s += part[((size_t)b * 32 + i) * ND + d];
  csum[(size_t)b * ND + d] = s;
  mean[(size_t)b * ND + d] = s * (1.0f / 4096.0f);
}

// ---------------- per-row stats + hi/lo split into swizzled tiles ----------------
__global__ __launch_bounds__(128)
void rowstats_kernel(const float* __restrict__ X, const float* __restrict__ W,
                     const float* __restrict__ mean,
                     u16* __restrict__ hi, u16* __restrict__ lo,
                     float* __restrict__ rv, float* __restrict__ xw) {
  const int n  = blockIdx.x;
  const int gb = blockIdx.y;
  const int tid = threadIdx.x;
  const float* xr = X + ((size_t)gb * NROW + n) * ND;
  const float* mb = mean + (size_t)gb * ND;
  const int r = n & 127, rbk = n >> 7;
  float ssq = 0.f, sw = 0.f;
  if (tid < 96) {
    const int d0 = tid * 8;
    const float4 xa = *(const float4*)(xr + d0);
    const float4 xb = *(const float4*)(xr + d0 + 4);
    const float4 ma = *(const float4*)(mb + d0);
    const float4 mc = *(const float4*)(mb + d0 + 4);
    const float4 wa = *(const float4*)(W + d0);
    const float4 wb = *(const float4*)(W + d0 + 4);
    float x[8]  = {xa.x, xa.y, xa.z, xa.w, xb.x, xb.y, xb.z, xb.w};
    float mm[8] = {ma.x, ma.y, ma.z, ma.w, mc.x, mc.y, mc.z, mc.w};
    float ww[8] = {wa.x, wa.y, wa.z, wa.w, wb.x, wb.y, wb.z, wb.w};
    u16 hbits[8], lbits[8];
#pragma unroll
    for (int i = 0; i < 8; ++i) {
      float xc = x[i] - mm[i];
      ssq += xc * xc;
      sw  += x[i] * ww[i];
      u16 hb = f2bf(xc);
      float hf = bf2f(hb);
      u16 lb2 = f2bf(xc - hf);
      hbits[i] = hb; lbits[i] = lb2;
    }
    const int kb = d0 >> 5;
    const int kk = d0 & 31;
    const size_t tbyte = ((size_t)((gb * NRB + rbk) * NKB + kb)) * 8192
                       + (size_t)((r * 64 + kk * 2) ^ ((r & 7) << 4));
    uint4 hv, lv;
    hv.x = (uint32_t)hbits[0] | ((uint32_t)hbits[1] << 16);
    hv.y = (uint32_t)hbits[2] | ((uint32_t)hbits[3] << 16);
    hv.z = (uint32_t)hbits[4] | ((uint32_t)hbits[5] << 16);
    hv.w = (uint32_t)hbits[6] | ((uint32_t)hbits[7] << 16);
    lv.x = (uint32_t)lbits[0] | ((uint32_t)lbits[1] << 16);
    lv.y = (uint32_t)lbits[2] | ((uint32_t)lbits[3] << 16);
    lv.z = (uint32_t)lbits[4] | ((uint32_t)lbits[5] << 16);
    lv.w = (uint32_t)lbits[6] | ((uint32_t)lbits[7] << 16);
    *(uint4*)((char*)hi + tbyte) = hv;
    *(uint4*)((char*)lo + tbyte) = lv;
  }
#pragma unroll
  for (int m = 1; m < 64; m <<= 1) {
    ssq += __shfl_xor(ssq, m, 64);
    sw  += __shfl_xor(sw, m, 64);
  }
  __shared__ float sh[4];
  const int w = tid >> 6, lane = tid & 63;
  if (lane == 0) { sh[w * 2] = ssq; sh[w * 2 + 1] = sw; }
  __syncthreads();
  if (tid == 0) {
    float S = sh[0] + sh[2];
    float T = sh[1] + sh[3];
    const size_t i = (size_t)gb * NROW + n;
    rv[i] = 1.0f / (sqrtf(S) + 1e-6f);
    xw[i] = T;
  }
}

// ---------------- triangular cov GEMM: t-reduction + |cov| fp32 store ----------------
static __device__ __forceinline__ bf16x8 read_frag(const u16* sm, int r, int kbyte) {
  const int byte = (r * 64 + kbyte) ^ ((r & 7) << 4);
  return *(const bf16x8*)((const char*)sm + byte);
}

__global__ __launch_bounds__(256, 2)
void gemm_acc_kernel(const u16* __restrict__ hi, const u16* __restrict__ lo,
                     const float* __restrict__ coef, float* __restrict__ outacc,
                     float* __restrict__ covout) {
  const int gb = blockIdx.y;
  const int tsw = tile_swz(blockIdx.x);
  int trem = tsw;
  int rb = 0;
  while (trem >= NRB - rb) { trem -= NRB - rb; ++rb; }
  const int cb = rb + trem;

  __shared__ u16 sm[4 * KTILE];     // 32 KiB: aHi | bHi | aLo | bLo
  u16* aHi = sm;
  u16* bHi = sm + KTILE;
  u16* aLo = sm + 2 * KTILE;
  u16* bLo = sm + 3 * KTILE;

  const int tid = threadIdx.x;
  const int lane = tid & 63;
  const int wid = tid >> 6;
  const int wrow = wid >> 1, wcol = wid & 1;
  const int l15 = lane & 15, lg = lane >> 4;

  const char* hA = (const char*)(hi + (size_t)((gb * NRB + rb) * NKB) * KTILE);
  const char* hB = (const char*)(hi + (size_t)((gb * NRB + cb) * NKB) * KTILE);
  const char* lA = (const char*)(lo + (size_t)((gb * NRB + rb) * NKB) * KTILE);
  const char* lB = (const char*)(lo + (size_t)((gb * NRB + cb) * NKB) * KTILE);

  f32x4 acc[4][4];
#pragma unroll
  for (int i = 0; i < 4; ++i)
#pragma unroll
    for (int j = 0; j < 4; ++j) acc[i][j] = f32x4{0.f, 0.f, 0.f, 0.f};

  for (int kb = 0; kb < NKB; ++kb) {
    __syncthreads();                       // all waves done reading previous tile
    const size_t kb8 = (size_t)kb * 8192;
#pragma unroll
    for (int it = 0; it < 2; ++it) {
      const int off = it * 4096 + tid * 16;
      gload_lds16(hA + kb8 + off, (char*)aHi + off);
      gload_lds16(hB + kb8 + off, (char*)bHi + off);
      gload_lds16(lA + kb8 + off, (char*)aLo + off);
      gload_lds16(lB + kb8 + off, (char*)bLo + off);
    }
    __syncthreads();                       // compiler drains vmcnt(0) -> LDS ready

    bf16x8 ah[4], bh[4], al[4], bl[4];
#pragma unroll
    for (int i = 0; i < 4; ++i) {
      ah[i] = read_frag(aHi, wrow * 64 + i * 16 + l15, lg * 16);
      bh[i] = read_frag(bHi, wcol * 64 + i * 16 + l15, lg * 16);
      al[i] = read_frag(aLo, wrow * 64 + i * 16 + l15, lg * 16);
      bl[i] = read_frag(bLo, wcol * 64 + i * 16 + l15, lg * 16);
    }
#pragma unroll
    for (int mi = 0; mi < 4; ++mi)
#pragma unroll
      for (int ni = 0; ni < 4; ++ni) {
        acc[mi][ni] = __builtin_amdgcn_mfma_f32_16x16x32_bf16(ah[mi], bh[ni], acc[mi][ni], 0, 0, 0);
        acc[mi][ni] = __builtin_amdgcn_mfma_f32_16x16x32_bf16(ah[mi], bl[ni], acc[mi][ni], 0, 0, 0);
        acc[mi][ni] = __builtin_amdgcn_mfma_f32_16x16x32_bf16(al[mi], bh[ni], acc[mi][ni], 0, 0, 0);
      }
  }

  const float* cf = coef + (size_t)gb * NROW;
  float* oa = outacc + (size_t)gb * NROW;
  const int rbase = rb * 128 + wrow * 64;
  const int cbase = cb * 128 + wcol * 64;

  // store |cov| tile (fp32, tile-linear 128x128) for the u-pass
  float* cv = covout + ((size_t)gb * NTRI + tsw) * 16384;
#pragma unroll
  for (int mi = 0; mi < 4; ++mi)
#pragma unroll
    for (int ni = 0; ni < 4; ++ni)
#pragma unroll
      for (int j = 0; j < 4; ++j)
        cv[(wrow * 64 + mi * 16 + lg * 4 + j) * 128 + wcol * 64 + ni * 16 + l15] =
            fabsf(acc[mi][ni][j]);

  // row-direction: t[row] += sum_cols |c| * coef[col]
  float ccol[4];
#pragma unroll
  for (int ni = 0; ni < 4; ++ni) ccol[ni] = cf[cbase + ni * 16 + l15];

  float rs[4][4];
#pragma unroll
  for (int mi = 0; mi < 4; ++mi)
#pragma unroll
    for (int j = 0; j < 4; ++j) {
      float s = 0.f;
#pragma unroll
      for (int ni = 0; ni < 4; ++ni) s += fabsf(acc[mi][ni][j]) * ccol[ni];
      rs[mi][j] = s;
    }
#pragma unroll
  for (int m = 1; m < 16; m <<= 1)
#pragma unroll
    for (int mi = 0; mi < 4; ++mi)
#pragma unroll
      for (int j = 0; j < 4; ++j) rs[mi][j] += __shfl_xor(rs[mi][j], m, 64);
  if (l15 == 0) {
#pragma unroll
    for (int mi = 0; mi < 4; ++mi)
#pragma unroll
      for (int j = 0; j < 4; ++j)
        atomicAdd(&oa[rbase + mi * 16 + lg * 4 + j], rs[mi][j]);
  }

  // col-direction (symmetry): off-diagonal tiles only
  if (rb != cb) {
    float crow[4][4];
#pragma unroll
    for (int mi = 0; mi < 4; ++mi)
#pragma unroll
      for (int j = 0; j < 4; ++j) crow[mi][j] = cf[rbase + mi * 16 + lg * 4 + j];
    float cs[4];
#pragma unroll
    for (int ni = 0; ni < 4; ++ni) {
      float s = 0.f;
#pragma unroll
      for (int mi = 0; mi < 4; ++mi)
#pragma unroll
        for (int j = 0; j < 4; ++j) s += fabsf(acc[mi][ni][j]) * crow[mi][j];
      cs[ni] = s;
    }
#pragma unroll
    for (int ni = 0; ni < 4; ++ni) {
      cs[ni] += __shfl_xor(cs[ni], 16, 64);
      cs[ni] += __shfl_xor(cs[ni], 32, 64);
    }
    if (lg == 0) {
#pragma unroll
      for (int ni = 0; ni < 4; ++ni)
        atomicAdd(&oa[cbase + ni * 16 + l15], cs[ni]);
    }
  }
}

// ---------------- u-pass: weighted row/col reduction of stored |cov| ----------------
__global__ __launch_bounds__(256, 2)
void upass_kernel(const float* __restrict__ cov, const float* __restrict__ tt,
                  const float* __restrict__ rv, const float* __restrict__ xw,
                  float* __restrict__ uacc) {
  const int gb = blockIdx.y;
  const int tsw = tile_swz(blockIdx.x);
  int trem = tsw;
  int rb = 0;
  while (trem >= NRB - rb) { trem -= NRB - rb; ++rb; }
  const int cb = rb + trem;

  const float* A = cov + ((size_t)gb * NTRI + tsw) * 16384;
  const size_t bo = (size_t)gb * NROW;

  __shared__ float wr[128];
  __shared__ float plds[128 * 33];       // [row][lane] partial row-dots, pad 33
  __shared__ float csum_p[8][128];

  const int t = threadIdx.x;
  const int g = t >> 5;          // 0..7
  const int l = t & 31;          // 0..31

  if (t < 128) {
    const int row = rb * 128 + t;
    wr[t] = (1.0f / sqrtf(rv[bo + row] * tt[bo + row])) * xw[bo + row] * rv[bo + row];
  }
  float4 wc4;
  {
    const int col = cb * 128 + l * 4;
    const float4 r4 = *(const float4*)(rv + bo + col);
    const float4 t4 = *(const float4*)(tt + bo + col);
    const float4 x4 = *(const float4*)(xw + bo + col);
    wc4.x = (1.0f / sqrtf(r4.x * t4.x)) * x4.x * r4.x;
    wc4.y = (1.0f / sqrtf(r4.y * t4.y)) * x4.y * r4.y;
    wc4.z = (1.0f / sqrtf(r4.z * t4.z)) * x4.z * r4.z;
    wc4.w = (1.0f / sqrtf(r4.w * t4.w)) * x4.w * r4.w;
  }
  __syncthreads();

  float sc0 = 0.f, sc1 = 0.f, sc2 = 0.f, sc3 = 0.f;
#pragma unroll
  for (int i = 0; i < 16; ++i) {
    const int r = g + i * 8;
    const f32x4 v = __builtin_nontemporal_load((const f32x4*)(A + r * 128 + l * 4));
    plds[r * 33 + l] = v[0] * wc4.x + v[1] * wc4.y + v[2] * wc4.z + v[3] * wc4.w;
    const float wrr = wr[r];
    sc0 += v[0] * wrr; sc1 += v[1] * wrr; sc2 += v[2] * wrr; sc3 += v[3] * wrr;
  }
  csum_p[g][l * 4 + 0] = sc0;
  csum_p[g][l * 4 + 1] = sc1;
  csum_p[g][l * 4 + 2] = sc2;
  csum_p[g][l * 4 + 3] = sc3;
  __syncthreads();

  float* ua = uacc + bo;
  if (t < 128) {
    float rsum = 0.f;
#pragma unroll
    for (int i = 0; i < 32; ++i) rsum += plds[t * 33 + i];
    atomicAdd(&ua[rb * 128 + t], rsum);
    if (rb != cb) {
      float s = 0.f;
#pragma unroll
      for (int gg = 0; gg < 8; ++gg) s += csum_p[gg][t];
      atomicAdd(&ua[cb * 128 + t], s);
    }
  }
}

// ---------------- top-k via radix-select (exact, deterministic) + gather + means ----------------
// Keys: (monotone-mapped S << 32) | (4095 - i). All keys distinct (index bits),
// so the 50th-largest key is unique; select it by byte-wise radix from MSB.
// ALL barriers are block-wide __syncthreads() (r13 crash: divergent s_barrier).
__global__ __launch_bounds__(1024)
void topk_kernel(const float* __restrict__ tt, const float* __restrict__ rv,
                 const float* __restrict__ u, const float* __restrict__ X,
                 const float* __restrict__ csum, float* __restrict__ S,
                 float* __restrict__ outFc, float* __restrict__ outC,
                 float* __restrict__ outNC) {
  const int b = blockIdx.x;
  __shared__ ull keys[NROW];
  __shared__ unsigned int hist[256];
  __shared__ unsigned int wsum[4];
  __shared__ ull spref;
  __shared__ int sR, seld;
  __shared__ int cnt;
  __shared__ ull cand[TOPK];
  __shared__ int selLds[TOPK];

  const int t = threadIdx.x;
  const int lane = t & 63, w = t >> 6;
  const size_t bo = (size_t)b * NROW;

#pragma unroll
  for (int j = 0; j < 4; ++j) {
    const int i = t + j * 1024;
    const float rvi = rv[bo + i];
    const float s = (1.0f / sqrtf(rvi * tt[bo + i])) * rvi * u[bo + i];
    S[bo + i] = s;
    uint32_t uu = __float_as_uint(s);
    uu = (uu & 0x80000000u) ? ~uu : (uu | 0x80000000u);
    keys[i] = ((ull)uu << 32) | (uint32_t)(4095 - i);
  }
  if (t == 0) { spref = 0ULL; sR = TOPK; cnt = 0; }
  __syncthreads();

  // 8 radix passes, MSB byte -> LSB byte
  for (int p = 7; p >= 0; --p) {
    if (t < 256) hist[t] = 0u;
    if (t == 0) seld = -1;
    __syncthreads();
    const ull pref = spref;
    const ull mask = (p == 7) ? 0ULL : (~0ULL << ((p + 1) * 8));
#pragma unroll
    for (int j = 0; j < 4; ++j) {
      const ull k = keys[t + j * 1024];
      if ((k & mask) == pref)
        atomicAdd(&hist[(unsigned int)(k >> (p * 8)) & 255u], 1u);
    }
    __syncthreads();
    // suffix sum s[t] = sum_{d>=t} hist[d]; threads 0..255 = waves 0..3 (full waves)
    unsigned int sv = 0;
    if (t < 256) {
      sv = hist[t];
#pragma unroll
      for (int off = 1; off < 64; off <<= 1) {
        unsigned int o = __shfl_down(sv, off, 64);
        if (lane + off < 64) sv += o;
      }
      if (lane == 0) wsum[w] = sv;   // wave-total (suffix from wave base)
    }
    __syncthreads();
    if (t < 256) {
      unsigned int add = 0;
#pragma unroll
      for (int ww = 0; ww < 4; ++ww)
        if (ww > w) add += wsum[ww];
      sv += add;                                // full suffix count for bin t
      if ((int)sv >= sR) atomicMax(&seld, t);   // largest bin d with suffix >= R
    }
    __syncthreads();
    if (t == seld) {
      sR = sR - (int)(sv - hist[t]);            // subtract strictly-greater count
      spref = spref | ((ull)(unsigned int)t << (p * 8));
    }
    __syncthreads();
  }
  const ull kth = spref;   // exact 50th-largest key

  // compact the exactly-50 keys >= kth
#pragma unroll
  for (int j = 0; j < 4; ++j) {
    const ull k = keys[t + j * 1024];
    if (k >= kth) {
      const int ppos = atomicAdd(&cnt, 1);
      cand[ppos] = k;
    }
  }
  __syncthreads();
  // rank the 50 (all distinct): rank = #greater
  if (t < TOPK) {
    const ull me = cand[t];
    int r = 0;
#pragma unroll 10
    for (int i = 0; i < TOPK; ++i) r += (cand[i] > me);
    selLds[r] = 4095 - (int)(me & 0xFFFFFFFFu);
  }
  __syncthreads();

  // gather + means with threads 0..767 (selection indices in LDS)
  if (t < ND) {
    float s = 0.f;
    for (int r = 0; r < TOPK; ++r) {
      const int row = selLds[r];
      const float v = X[(bo + row) * ND + t];
      outFc[((size_t)b * TOPK + r) * ND + t] = v;
      s += v;
    }
    outC[(size_t)b * ND + t]  = s * (1.0f / 50.0f);
    outNC[(size_t)b * ND + t] = (csum[(size_t)b * ND + t] - s) * (1.0f / 4046.0f);
  }
}

// ---------------- launch ----------------
extern "C" void kernel_launch(void* const* d_in, const int* in_sizes, int n_in,
                              void* d_out, int out_size, void* d_ws, size_t ws_size,
                              hipStream_t stream) {
  const float* X = (const float*)d_in[0];
  const float* W = (const float*)d_in[1];
  float* out = (float*)d_out;
  char* ws = (char*)d_ws;

  float* cpart = (float*)(ws + CPART_OFF);
  float* csum  = (float*)(ws + CSUM_OFF);
  float* mean  = (float*)(ws + MEAN_OFF);
  float* rv    = (float*)(ws + RV_OFF);
  float* xw    = (float*)(ws + XW_OFF);
  float* tacc  = (float*)(ws + T_OFF);
  float* uacc  = (float*)(ws + U_OFF);
  u16* hi      = (u16*)(ws + HI_OFF);
  u16* lo      = (u16*)(ws + LO_OFF);
  float* cov   = (float*)(ws + COV_OFF);

  float* outS  = out;                       // 8*4096
  float* outFc = out + 32768;               // 8*50*768
  float* outMC = out + 339968;              // 8*768
  float* outMN = out + 346112;              // 8*768

  // zero the atomic accumulators (t and u are adjacent)
  hipMemsetAsync(ws + T_OFF, 0, 262144, stream);

  colsum1_kernel<<<dim3(32, 3, NB), 256, 0, stream>>>(X, cpart);
  colsum2_kernel<<<dim3(3, NB), 256, 0, stream>>>(cpart, csum, mean);
  rowstats_kernel<<<dim3(NROW, NB), 128, 0, stream>>>(X, W, mean, hi, lo, rv, xw);
  gemm_acc_kernel<<<dim3(NTRI, NB), 256, 0, stream>>>(hi, lo, rv, tacc, cov);
  upass_kernel<<<dim3(NTRI, NB), 256, 0, stream>>>(cov, tacc, rv, xw, uacc);
  topk_kernel<<<NB, 1024, 0, stream>>>(tacc, rv, uacc, X, csum, outS, outFc, outMC, outMN);
}